// Round 3
// baseline (68.184 us; speedup 1.0000x reference)
//
#include <hip/hip_runtime.h>
#include <hip/hip_bf16.h>

// BallPredictorGNN: 2-layer GAT + MLP head; output depends ONLY on node N-1.
// Prune to the 2-hop incoming neighborhood of the ball node.
//   S1 = in-neighbors of ball (+ ball)             [~34 nodes]
//   S2 = one row PER EDGE into S1 (+ S1 selfloops) [~2150 rows, dups allowed]
// nbr[] buckets store S2 ROW indices directly (no inv2 indirection).
// 5 kernels; final ball aggregation fused into k456 via completion counter.

#define NEG_SLOPE 0.2f
constexpr int F_IN  = 128;
constexpr int HEADS = 4;
constexpr int CH    = 64;
constexpr int D1    = 256;   // HEADS*CH

constexpr int CAP1   = 512;   // |S1| cap (expected ~34)
constexpr int CAP2   = 4096;  // S2 row cap (expected ~2150)
constexpr int CAPE0  = 2048;  // ball in-edge cap (expected ~32)
constexpr int MAXDEG = 256;   // per-S1-node in-degree cap (expected ~33)
constexpr int ROWS3  = 8;     // S2 rows per k3 block

struct Ws {
    int* meta;     // [0]=count1 [1]=rows2 [2]=cntE0 [4]=completion
    int* flag1;    // [N]
    int* inv1;     // [N]
    int* list1;    // [CAP1]  node ids of S1
    int* dstrow;   // [CAP1]  S2 row holding S1 node t's own h1
    int* list2;    // [CAP2]  node id per S2 row
    int* e0;       // [CAPE0] srcs of ball edges (node ids, then S1 indices)
    int* deg;      // [CAP1]
    int* nbr;      // [CAP1*MAXDEG]  S2 row indices
    float* H1c;    // [CAP2*D1]
    float* as1;    // [CAP2*HEADS]
    float* ad1;    // [CAP2*HEADS]
    float* h2c;    // [CAP1*CH]
    float* as2;    // [CAP1]
    float* ad2;    // [CAP1]
};

__global__ void k0_init(Ws w, int N, int ball) {
    int i = blockIdx.x * blockDim.x + threadIdx.x;
    if (i < N) {
        w.flag1[i] = (i == ball) ? 1 : 0;
        if (i == ball) w.inv1[i] = 0;
    }
    if (i < CAP1) w.deg[i] = 0;
    if (i == 0) {
        w.meta[0] = 1;   // ball pre-seeded as S1 index 0
        w.meta[1] = 0;
        w.meta[2] = 0;
        w.meta[4] = 0;   // completion counter for k456
        w.list1[0] = ball;
    }
}

// scan edges for dst == ball; build S1 (dedup via flag1)
__global__ void k1_ball_edges(Ws w, const int* __restrict__ src,
                              const int* __restrict__ dst, int E, int ball) {
    int t = blockIdx.x * blockDim.x + threadIdx.x;
    int e0 = t * 4;
    if (e0 >= E) return;
    int4 dv = *(const int4*)&dst[e0];
    int dd[4] = {dv.x, dv.y, dv.z, dv.w};
#pragma unroll
    for (int k = 0; k < 4; k++) {
        int e = e0 + k;
        if (e < E && dd[k] == ball) {
            int s = src[e];
            int p = atomicAdd(&w.meta[2], 1);
            if (p < CAPE0) w.e0[p] = s;
            if (atomicExch(&w.flag1[s], 1) == 0) {
                int q = atomicAdd(&w.meta[0], 1);
                if (q < CAP1) { w.list1[q] = s; w.inv1[s] = q; }
            }
        }
    }
}

// prologue: S1 selfloop rows + e0 node->S1-index conversion.
// main: scan edges for dst in S1; one S2 row per edge; bucket row into nbr.
__global__ void k2_l1_edges(Ws w, const int* __restrict__ src,
                            const int* __restrict__ dst, int E) {
    int gt = blockIdx.x * blockDim.x + threadIdx.x;
    int c1 = min(w.meta[0], CAP1);
    if (gt < c1) {
        int v = w.list1[gt];
        int q = atomicAdd(&w.meta[1], 1);
        if (q < CAP2) {
            w.list2[q] = v;
            w.dstrow[gt] = q;
            int p = atomicAdd(&w.deg[gt], 1);
            if (p < MAXDEG) w.nbr[gt * MAXDEG + p] = q;
        }
    }
    int ne = min(w.meta[2], CAPE0);
    if (gt < ne) w.e0[gt] = w.inv1[w.e0[gt]];

    int e0i = gt * 4;
    if (e0i >= E) return;
    int4 dv = *(const int4*)&dst[e0i];
    int dd[4] = {dv.x, dv.y, dv.z, dv.w};
#pragma unroll
    for (int k = 0; k < 4; k++) {
        int e = e0i + k;
        if (e < E && w.flag1[dd[k]]) {
            int s = src[e];
            int di = w.inv1[dd[k]];
            int q = atomicAdd(&w.meta[1], 1);
            if (q < CAP2) {
                w.list2[q] = s;
                int p = atomicAdd(&w.deg[di], 1);
                if (p < MAXDEG) w.nbr[di * MAXDEG + p] = q;
            }
        }
    }
}

// h1 = x@W1 per S2 row (8 rows/block: W1 loads reused x8); alpha_s1/alpha_d1
__global__ __launch_bounds__(256) void k3_h1(Ws w, const float* __restrict__ x,
                                             const float* __restrict__ W1,
                                             const float* __restrict__ a_s,
                                             const float* __restrict__ a_d) {
    int c2 = min(w.meta[1], CAP2);
    int base = blockIdx.x * ROWS3;
    if (base >= c2) return;
    __shared__ float xs[ROWS3][F_IN];
    int j = threadIdx.x;
    for (int t = j; t < ROWS3 * F_IN; t += 256) {
        int r = t >> 7, kk = t & 127;
        int idx = base + r;
        xs[r][kk] = (idx < c2) ? x[(size_t)w.list2[idx] * F_IN + kk] : 0.f;
    }
    __syncthreads();
    float acc[ROWS3];
#pragma unroll
    for (int r = 0; r < ROWS3; r++) acc[r] = 0.f;
#pragma unroll 4
    for (int k = 0; k < F_IN; k++) {
        float wv = W1[k * D1 + j];
#pragma unroll
        for (int r = 0; r < ROWS3; r++) acc[r] += xs[r][k] * wv;
    }
    int hh = j >> 6, cc = j & 63;
    float asv = a_s[hh * CH + cc], adv = a_d[hh * CH + cc];
#pragma unroll
    for (int r = 0; r < ROWS3; r++) {
        int idx = base + r;
        if (idx < c2) {
            w.H1c[idx * D1 + j] = acc[r];
            float vs = acc[r] * asv;
            float vd = acc[r] * adv;
            for (int o = 32; o > 0; o >>= 1) {
                vs += __shfl_xor(vs, o, 64);
                vd += __shfl_xor(vd, o, 64);
            }
            if (cc == 0) { w.as1[idx * HEADS + hh] = vs; w.ad1[idx * HEADS + hh] = vd; }
        }
    }
}

// Layer-1 GAT agg per S1 node + h2/alpha2 (fused), then the LAST completing
// block runs the ball-node layer-2 aggregation + MLP head.
__global__ __launch_bounds__(256) void k456(Ws w, const float* __restrict__ b1,
                                            const float* __restrict__ W2,
                                            const float* __restrict__ a_s2,
                                            const float* __restrict__ a_d2,
                                            const float* __restrict__ b2,
                                            const float* __restrict__ fc1w,
                                            const float* __restrict__ fc1b,
                                            const float* __restrict__ fc2w,
                                            const float* __restrict__ fc2b,
                                            float* __restrict__ out) {
    int b = blockIdx.x;
    int c1 = min(w.meta[0], CAP1);
    int tid = threadIdx.x;
    __shared__ int   sI2[MAXDEG];
    __shared__ float sW[MAXDEG][HEADS];
    __shared__ float sSum[HEADS];
    __shared__ float sO1[D1];
    __shared__ int   sLast;

    if (b < c1) {
        int i2d = w.dstrow[b];
        int deg = min(w.deg[b], MAXDEG);
        for (int p = tid; p < deg; p += 256) sI2[p] = w.nbr[b * MAXDEG + p];
        __syncthreads();
        for (int t = tid; t < deg * HEADS; t += 256) {
            int p = t >> 2, h = t & 3;
            float e = w.as1[sI2[p] * HEADS + h] + w.ad1[i2d * HEADS + h];
            sW[p][h] = e > 0.f ? e : NEG_SLOPE * e;
        }
        __syncthreads();
        int wv = tid >> 6, ln = tid & 63;
        {   // per-head softmax: wave wv handles head wv
            float m = -1e30f;
            for (int p = ln; p < deg; p += 64) m = fmaxf(m, sW[p][wv]);
            for (int o = 32; o > 0; o >>= 1) m = fmaxf(m, __shfl_xor(m, o, 64));
            float s = 0.f;
            for (int p = ln; p < deg; p += 64) {
                float wt = expf(sW[p][wv] - m);
                sW[p][wv] = wt;
                s += wt;
            }
            for (int o = 32; o > 0; o >>= 1) s += __shfl_xor(s, o, 64);
            if (ln == 0) sSum[wv] = s;
        }
        __syncthreads();
        int h = wv, c = ln;
        float acc = 0.f;
#pragma unroll 4
        for (int p = 0; p < deg; p++)
            acc += sW[p][h] * w.H1c[sI2[p] * D1 + h * CH + c];
        float o1 = acc / (sSum[h] + 1e-16f) + b1[h * CH + c];
        sO1[h * CH + c] = o1 > 0.f ? o1 : 0.f;
        __syncthreads();
        if (tid < 64) {
            float a2 = 0.f;
#pragma unroll 8
            for (int k = 0; k < D1; k++) a2 += sO1[k] * W2[k * CH + tid];
            w.h2c[b * CH + tid] = a2;
            float vs = a2 * a_s2[tid];
            float vd = a2 * a_d2[tid];
            for (int o = 32; o > 0; o >>= 1) {
                vs += __shfl_xor(vs, o, 64);
                vd += __shfl_xor(vd, o, 64);
            }
            if (tid == 0) { w.as2[b] = vs; w.ad2[b] = vd; }
        }
    }

    // ---- completion detection: last block runs the ball aggregation ----
    __syncthreads();
    if (tid == 0) {
        __threadfence();
        int done = __hip_atomic_fetch_add(&w.meta[4], 1, __ATOMIC_ACQ_REL,
                                          __HIP_MEMORY_SCOPE_AGENT);
        sLast = (done == (int)gridDim.x - 1) ? 1 : 0;
    }
    __syncthreads();
    if (!sLast) return;
    __threadfence();

    __shared__ float tWt[CAPE0 + 1];
    __shared__ int   tIdx[CAPE0];
    __shared__ float ball_v[CH];
    __shared__ float z[32];
    int ne = min(w.meta[2], CAPE0);
    for (int i = tid; i < ne; i += 256) tIdx[i] = w.e0[i];  // S1 indices
    __syncthreads();
    if (tid < 64) {
        float adv = w.ad2[0];  // ball is S1 index 0
        float m = -1e30f;
        for (int i = tid; i <= ne; i += 64) {
            int i1 = (i < ne) ? tIdx[i] : 0;
            float e = w.as2[i1] + adv;
            e = e > 0.f ? e : NEG_SLOPE * e;
            m = fmaxf(m, e);
        }
        for (int o = 32; o > 0; o >>= 1) m = fmaxf(m, __shfl_xor(m, o, 64));
        float ss = 0.f;
        for (int i = tid; i <= ne; i += 64) {
            int i1 = (i < ne) ? tIdx[i] : 0;
            float e = w.as2[i1] + adv;
            e = e > 0.f ? e : NEG_SLOPE * e;
            float wt = expf(e - m);
            tWt[i] = wt;
            ss += wt;
        }
        for (int o = 32; o > 0; o >>= 1) ss += __shfl_xor(ss, o, 64);
        float acc = 0.f;  // lane = channel
#pragma unroll 4
        for (int i = 0; i <= ne; i++) {
            int i1 = (i < ne) ? tIdx[i] : 0;
            acc += tWt[i] * w.h2c[i1 * CH + tid];
        }
        float bv = acc / (ss + 1e-16f) + b2[tid];
        ball_v[tid] = bv > 0.f ? bv : 0.f;
    }
    __syncthreads();
    if (tid < 32) {
        float a = fc1b[tid];
#pragma unroll 8
        for (int c = 0; c < CH; c++) a += ball_v[c] * fc1w[c * 32 + tid];
        z[tid] = a > 0.f ? a : 0.f;
    }
    __syncthreads();
    if (tid < 2) {
        float a = fc2b[tid];
#pragma unroll 8
        for (int k = 0; k < 32; k++) a += z[k] * fc2w[k * 2 + tid];
        out[tid] = a;
    }
}

extern "C" void kernel_launch(void* const* d_in, const int* in_sizes, int n_in,
                              void* d_out, int out_size, void* d_ws, size_t ws_size,
                              hipStream_t stream) {
    const float* x    = (const float*)d_in[0];
    const int*   ei   = (const int*)d_in[1];
    const float* W1   = (const float*)d_in[2];
    const float* as1w = (const float*)d_in[3];
    const float* ad1w = (const float*)d_in[4];
    const float* b1   = (const float*)d_in[5];
    const float* W2   = (const float*)d_in[6];
    const float* as2w = (const float*)d_in[7];
    const float* ad2w = (const float*)d_in[8];
    const float* b2   = (const float*)d_in[9];
    const float* fc1w = (const float*)d_in[10];
    const float* fc1b = (const float*)d_in[11];
    const float* fc2w = (const float*)d_in[12];
    const float* fc2b = (const float*)d_in[13];

    int E = in_sizes[1] / 2;
    int N = in_sizes[0] / F_IN;
    int ball = N - 1;
    const int* srcA = ei;
    const int* dstA = ei + E;

    char* p = (char*)d_ws;
    auto carve = [&](size_t bytes) {
        void* r = (void*)p;
        p += (bytes + 255) & ~(size_t)255;
        return r;
    };
    Ws w;
    w.meta   = (int*)carve(16 * sizeof(int));
    w.flag1  = (int*)carve((size_t)N * sizeof(int));
    w.inv1   = (int*)carve((size_t)N * sizeof(int));
    w.list1  = (int*)carve(CAP1 * sizeof(int));
    w.dstrow = (int*)carve(CAP1 * sizeof(int));
    w.list2  = (int*)carve(CAP2 * sizeof(int));
    w.e0     = (int*)carve(CAPE0 * sizeof(int));
    w.deg    = (int*)carve(CAP1 * sizeof(int));
    w.nbr    = (int*)carve((size_t)CAP1 * MAXDEG * sizeof(int));
    w.H1c    = (float*)carve((size_t)CAP2 * D1 * sizeof(float));
    w.as1    = (float*)carve((size_t)CAP2 * HEADS * sizeof(float));
    w.ad1    = (float*)carve((size_t)CAP2 * HEADS * sizeof(float));
    w.h2c    = (float*)carve((size_t)CAP1 * CH * sizeof(float));
    w.as2    = (float*)carve(CAP1 * sizeof(float));
    w.ad2    = (float*)carve(CAP1 * sizeof(float));

    int gE4 = (E / 4 + 255) / 256;
    k0_init<<<(N + 255) / 256, 256, 0, stream>>>(w, N, ball);
    k1_ball_edges<<<gE4, 256, 0, stream>>>(w, srcA, dstA, E, ball);
    k2_l1_edges<<<gE4, 256, 0, stream>>>(w, srcA, dstA, E);
    k3_h1<<<CAP2 / ROWS3, 256, 0, stream>>>(w, x, W1, as1w, ad1w);
    k456<<<CAP1, 256, 0, stream>>>(w, b1, W2, as2w, ad2w, b2,
                                   fc1w, fc1b, fc2w, fc2b, (float*)d_out);
}